// Round 1
// baseline (501.398 us; speedup 1.0000x reference)
//
#include <hip/hip_runtime.h>
#include <hip/hip_bf16.h>
#include <stdint.h>

#define N_ROWS 131072
#define K_CL   512
#define D_DIM  512
#define M_TILE 64
#define BK     32
#define STEPS  (D_DIM / BK)   // 16

typedef __attribute__((ext_vector_type(8))) short short8;
typedef __attribute__((ext_vector_type(4))) float f32x4;

__device__ __forceinline__ unsigned short f2bf(float f) {
  union { float f; unsigned u; } v; v.f = f;
  unsigned r = v.u + 0x7fffu + ((v.u >> 16) & 1u);
  return (unsigned short)(r >> 16);
}

__device__ __forceinline__ void glds16(const void* g, void* l) {
  __builtin_amdgcn_global_load_lds(
      (const __attribute__((address_space(1))) void*)g,
      (__attribute__((address_space(3))) void*)l, 16, 0, 0);
}

// --- prep: clusters fp32 -> bf16 (row-major, same layout) + c2 = ||c||^2 ---
__global__ void prep_clusters(const float* __restrict__ c,
                              unsigned short* __restrict__ cb,
                              float* __restrict__ c2) {
  const int b = blockIdx.x;   // cluster row 0..511
  const int l = threadIdx.x;  // 0..63
  const float* row = c + (size_t)b * D_DIM;
  float s = 0.f;
  #pragma unroll
  for (int i = 0; i < 2; ++i) {
    const int col = i * 256 + l * 4;
    float4 v = *(const float4*)(row + col);
    s += v.x * v.x + v.y * v.y + v.z * v.z + v.w * v.w;
    *(ushort4*)(cb + (size_t)b * D_DIM + col) =
        make_ushort4(f2bf(v.x), f2bf(v.y), f2bf(v.z), f2bf(v.w));
  }
  #pragma unroll
  for (int m = 1; m < 64; m <<= 1) s += __shfl_xor(s, m);
  if (l == 0) c2[b] = s;
}

// --- main: 64-row x 512-col tile per block, fused distance+softmax-normalize ---
__global__ __launch_bounds__(256, 2)
void cluster_main(const float* __restrict__ x,
                  const unsigned short* __restrict__ cb,
                  const float* __restrict__ c2,
                  float* __restrict__ out) {
  // LDS: Bs unpadded (global_load_lds constraint), As padded 32->40 to break bank conflicts
  __shared__ short As[M_TILE * 40];          // 5120 B
  __shared__ short Bs[4 * 128 * BK];         // 32768 B, per-wave 128x32 slices
  __shared__ float c2s[K_CL];                // 2048 B
  __shared__ float x2s[M_TILE];              // 256 B
  __shared__ float rowsum[4][M_TILE];        // 1024 B
  __shared__ float rinv[M_TILE];             // 256 B

  const int t = threadIdx.x;
  const int w = t >> 6;        // wave 0..3 -> col slice [w*128, w*128+128)
  const int l = t & 63;
  const int row0 = blockIdx.x * M_TILE;

  // stage c2 into LDS (visible after the K-loop barriers)
  c2s[t] = c2[t];
  c2s[t + 256] = c2[t + 256];

  f32x4 acc[4][8];
  #pragma unroll
  for (int i = 0; i < 4; ++i)
    #pragma unroll
    for (int j = 0; j < 8; ++j) acc[i][j] = (f32x4){0.f, 0.f, 0.f, 0.f};

  // A staging assignment: each thread loads 2 float4 (rows rowA, rowA+32)
  const int rowA = t >> 3;           // 0..31
  const int rowB = rowA + 32;
  const int kc   = (t & 7) * 4;      // k-offset within BK
  float ssA = 0.f, ssB = 0.f;

  short* BsW = &Bs[w * 128 * BK];

  for (int kk = 0; kk < STEPS; ++kk) {
    __syncthreads();  // prior iteration's LDS reads done

    // A global loads first so their vmcnt retires before the glds batch
    const float4 va = *(const float4*)(x + (size_t)(row0 + rowA) * D_DIM + kk * BK + kc);
    const float4 vb = *(const float4*)(x + (size_t)(row0 + rowB) * D_DIM + kk * BK + kc);

    // B slice: 8 x global_load_lds(16B) per wave; lane l -> LDS base + l*16
    #pragma unroll
    for (int i = 0; i < 8; ++i) {
      const int cg = w * 128 + i * 16 + (l >> 2);
      const unsigned short* g = cb + (size_t)cg * D_DIM + kk * BK + (l & 3) * 8;
      glds16(g, BsW + i * 16 * BK);
    }

    ssA += va.x * va.x + va.y * va.y + va.z * va.z + va.w * va.w;
    ssB += vb.x * vb.x + vb.y * vb.y + vb.z * vb.z + vb.w * vb.w;
    *(ushort4*)&As[rowA * 40 + kc] =
        make_ushort4(f2bf(va.x), f2bf(va.y), f2bf(va.z), f2bf(va.w));
    *(ushort4*)&As[rowB * 40 + kc] =
        make_ushort4(f2bf(vb.x), f2bf(vb.y), f2bf(vb.z), f2bf(vb.w));

    __syncthreads();  // staging visible (implicit vmcnt/lgkm drain covers glds)

    short8 a[4];
    #pragma unroll
    for (int rt = 0; rt < 4; ++rt)
      a[rt] = *(const short8*)&As[(rt * 16 + (l & 15)) * 40 + (l >> 4) * 8];

    #pragma unroll
    for (int ct = 0; ct < 8; ++ct) {
      short8 b = *(const short8*)&BsW[(ct * 16 + (l & 15)) * BK + (l >> 4) * 8];
      #pragma unroll
      for (int rt = 0; rt < 4; ++rt)
        acc[rt][ct] = __builtin_amdgcn_mfma_f32_16x16x32_bf16(a[rt], b, acc[rt][ct], 0, 0, 0);
    }
  }

  // ||x||^2 per row: reduce within 8-lane groups (same row), fp32-exact
  float s1 = ssA, s2 = ssB;
  s1 += __shfl_xor(s1, 1); s1 += __shfl_xor(s1, 2); s1 += __shfl_xor(s1, 4);
  s2 += __shfl_xor(s2, 1); s2 += __shfl_xor(s2, 2); s2 += __shfl_xor(s2, 4);
  if ((t & 7) == 0) { x2s[rowA] = s1; x2s[rowB] = s2; }
  __syncthreads();

  const int lg = l >> 4;   // lane group 0..3
  const int ln = l & 15;   // col within 16-tile

  float xr[4][4];
  #pragma unroll
  for (int rt = 0; rt < 4; ++rt)
    #pragma unroll
    for (int r = 0; r < 4; ++r) xr[rt][r] = x2s[rt * 16 + lg * 4 + r];
  float cv[8];
  #pragma unroll
  for (int ct = 0; ct < 8; ++ct) cv[ct] = c2s[w * 128 + ct * 16 + ln];

  float rp[4][4];
  #pragma unroll
  for (int rt = 0; rt < 4; ++rt)
    #pragma unroll
    for (int r = 0; r < 4; ++r) rp[rt][r] = 0.f;

  // q_unnorm = 1/(1 + d2), accumulate per-row partials; overwrite acc with q
  #pragma unroll
  for (int rt = 0; rt < 4; ++rt)
    #pragma unroll
    for (int ct = 0; ct < 8; ++ct) {
      f32x4 s = acc[rt][ct], q;
      #pragma unroll
      for (int r = 0; r < 4; ++r) {
        float d2 = xr[rt][r] + cv[ct] - 2.f * s[r];
        d2 = fmaxf(d2, 0.f);
        float qq = __builtin_amdgcn_rcpf(1.f + d2);
        q[r] = qq;
        rp[rt][r] += qq;
      }
      acc[rt][ct] = q;
    }

  // reduce row partials across the 16 lanes that hold different cols
  #pragma unroll
  for (int m = 1; m < 16; m <<= 1)
    #pragma unroll
    for (int rt = 0; rt < 4; ++rt)
      #pragma unroll
      for (int r = 0; r < 4; ++r) rp[rt][r] += __shfl_xor(rp[rt][r], m);

  if (ln == 0)
    #pragma unroll
    for (int rt = 0; rt < 4; ++rt)
      #pragma unroll
      for (int r = 0; r < 4; ++r)
        rowsum[w][rt * 16 + lg * 4 + r] = rp[rt][r];
  __syncthreads();

  if (t < M_TILE) {
    float tot = rowsum[0][t] + rowsum[1][t] + rowsum[2][t] + rowsum[3][t];
    rinv[t] = __builtin_amdgcn_rcpf(tot);
  }
  __syncthreads();

  float ri[4][4];
  #pragma unroll
  for (int rt = 0; rt < 4; ++rt)
    #pragma unroll
    for (int r = 0; r < 4; ++r) ri[rt][r] = rinv[rt * 16 + lg * 4 + r];

  #pragma unroll
  for (int rt = 0; rt < 4; ++rt)
    #pragma unroll
    for (int ct = 0; ct < 8; ++ct)
      #pragma unroll
      for (int r = 0; r < 4; ++r)
        out[(size_t)(row0 + rt * 16 + lg * 4 + r) * K_CL + w * 128 + ct * 16 + ln] =
            acc[rt][ct][r] * ri[rt][r];
}

extern "C" void kernel_launch(void* const* d_in, const int* in_sizes, int n_in,
                              void* d_out, int out_size, void* d_ws, size_t ws_size,
                              hipStream_t stream) {
  const float* x        = (const float*)d_in[0];
  const float* clusters = (const float*)d_in[1];
  float* out = (float*)d_out;

  // workspace layout: [clusters_bf16: 512*512*2B][c2: 512*4B] = 526336 B
  unsigned short* cb = (unsigned short*)d_ws;
  float* c2 = (float*)((char*)d_ws + (size_t)K_CL * D_DIM * sizeof(unsigned short));

  prep_clusters<<<K_CL, 64, 0, stream>>>(clusters, cb, c2);
  cluster_main<<<N_ROWS / M_TILE, 256, 0, stream>>>(x, cb, c2, out);
}

// Round 2
// 498.749 us; speedup vs baseline: 1.0053x; 1.0053x over previous
//
#include <hip/hip_runtime.h>
#include <hip/hip_bf16.h>
#include <stdint.h>

#define N_ROWS 131072
#define K_CL   512
#define D_DIM  512
#define M_TILE 64
#define BK     32
#define STEPS  (D_DIM / BK)   // 16

typedef __attribute__((ext_vector_type(8))) short short8;
typedef __attribute__((ext_vector_type(4))) float f32x4;

__device__ __forceinline__ unsigned short f2bf(float f) {
  union { float f; unsigned u; } v; v.f = f;
  unsigned r = v.u + 0x7fffu + ((v.u >> 16) & 1u);
  return (unsigned short)(r >> 16);
}

// --- prep 1: c2 = ||c||^2 per cluster row ---
__global__ void prep_c2(const float* __restrict__ c, float* __restrict__ c2) {
  const int b = blockIdx.x;   // cluster row 0..511
  const int l = threadIdx.x;  // 0..63
  const float* row = c + (size_t)b * D_DIM;
  float s = 0.f;
  #pragma unroll
  for (int i = 0; i < 2; ++i) {
    const int col = i * 256 + l * 4;
    float4 v = *(const float4*)(row + col);
    s += v.x * v.x + v.y * v.y + v.z * v.z + v.w * v.w;
  }
  #pragma unroll
  for (int m = 1; m < 64; m <<= 1) s += __shfl_xor(s, m);
  if (l == 0) c2[b] = s;
}

// --- prep 2: pack clusters fp32 -> bf16 in MFMA B-fragment order ---
// pb[(kk*32 + c16)*64 + lane] (16B each) = B[c16*16 + (lane&15)][kk*32 + (lane>>4)*8 + j]
__global__ void pack_b(const float* __restrict__ c, unsigned short* __restrict__ pb) {
  const int bid = blockIdx.x;       // = kk*32 + c16, 0..511
  const int c16 = bid & 31;
  const int kk  = bid >> 5;
  const int l   = threadIdx.x;      // 0..63
  const int row = c16 * 16 + (l & 15);
  const int k0  = kk * 32 + (l >> 4) * 8;
  float4 v0 = *(const float4*)(c + (size_t)row * D_DIM + k0);
  float4 v1 = *(const float4*)(c + (size_t)row * D_DIM + k0 + 4);
  ushort4 u0 = make_ushort4(f2bf(v0.x), f2bf(v0.y), f2bf(v0.z), f2bf(v0.w));
  ushort4 u1 = make_ushort4(f2bf(v1.x), f2bf(v1.y), f2bf(v1.z), f2bf(v1.w));
  *(ushort4*)(pb + (size_t)(bid * 64 + l) * 8)     = u0;
  *(ushort4*)(pb + (size_t)(bid * 64 + l) * 8 + 4) = u1;
}

// --- main: 64-row x 512-col tile per block; B fragments straight from L2 ---
__global__ __launch_bounds__(256, 2)
void cluster_main(const float* __restrict__ x,
                  const unsigned short* __restrict__ pb,
                  const float* __restrict__ c2,
                  float* __restrict__ out) {
  __shared__ short As[2][M_TILE * 40];       // double-buffered, padded 32->40
  __shared__ float c2s[K_CL];
  __shared__ float x2s[M_TILE];
  __shared__ float rowsum[4][M_TILE];
  __shared__ float rinv[M_TILE];

  const int t = threadIdx.x;
  const int w = t >> 6;        // wave 0..3 -> col slice [w*128, w*128+128)
  const int l = t & 63;
  const int row0 = blockIdx.x * M_TILE;

  c2s[t] = c2[t];
  c2s[t + 256] = c2[t + 256];

  f32x4 acc[4][8];
  #pragma unroll
  for (int i = 0; i < 4; ++i)
    #pragma unroll
    for (int j = 0; j < 8; ++j) acc[i][j] = (f32x4){0.f, 0.f, 0.f, 0.f};

  // A staging: each thread loads 2 float4 (rows rowA, rowA+32), k-offset kc
  const int rowA = t >> 3;           // 0..31
  const int rowB = rowA + 32;
  const int kc   = (t & 7) * 4;
  float ssA = 0.f, ssB = 0.f;

  const float* xA = x + (size_t)(row0 + rowA) * D_DIM + kc;
  const float* xB = x + (size_t)(row0 + rowB) * D_DIM + kc;

  // prologue: prefetch step-0 A into registers
  float4 va = *(const float4*)(xA);
  float4 vb = *(const float4*)(xB);

  int cur = 0;
  for (int kk = 0; kk < STEPS; ++kk) {
    // stage current A registers -> LDS, accumulate ||x||^2 in fp32
    ssA += va.x * va.x + va.y * va.y + va.z * va.z + va.w * va.w;
    ssB += vb.x * vb.x + vb.y * vb.y + vb.z * vb.z + vb.w * vb.w;
    *(ushort4*)&As[cur][rowA * 40 + kc] =
        make_ushort4(f2bf(va.x), f2bf(va.y), f2bf(va.z), f2bf(va.w));
    *(ushort4*)&As[cur][rowB * 40 + kc] =
        make_ushort4(f2bf(vb.x), f2bf(vb.y), f2bf(vb.z), f2bf(vb.w));

    // register-prefetch next step's A (hides HBM latency behind this step's MFMA)
    if (kk + 1 < STEPS) {
      va = *(const float4*)(xA + (kk + 1) * BK);
      vb = *(const float4*)(xB + (kk + 1) * BK);
    }

    // B fragments for this step: 8 fully-coalesced 16B loads/lane from L2-resident pb
    short8 b[8];
    #pragma unroll
    for (int ct = 0; ct < 8; ++ct)
      b[ct] = *(const short8*)(pb + ((size_t)(kk * 32 + w * 8 + ct) * 64 + l) * 8);

    __syncthreads();  // As[cur] staging visible (single barrier per K-step)

    short8 a[4];
    #pragma unroll
    for (int rt = 0; rt < 4; ++rt)
      a[rt] = *(const short8*)&As[cur][(rt * 16 + (l & 15)) * 40 + (l >> 4) * 8];

    #pragma unroll
    for (int ct = 0; ct < 8; ++ct)
      #pragma unroll
      for (int rt = 0; rt < 4; ++rt)
        acc[rt][ct] = __builtin_amdgcn_mfma_f32_16x16x32_bf16(a[rt], b[ct], acc[rt][ct], 0, 0, 0);

    cur ^= 1;
  }

  // ||x||^2 per row: reduce within 8-lane groups (same row), fp32-exact
  float s1 = ssA, s2 = ssB;
  s1 += __shfl_xor(s1, 1); s1 += __shfl_xor(s1, 2); s1 += __shfl_xor(s1, 4);
  s2 += __shfl_xor(s2, 1); s2 += __shfl_xor(s2, 2); s2 += __shfl_xor(s2, 4);
  if ((t & 7) == 0) { x2s[rowA] = s1; x2s[rowB] = s2; }
  __syncthreads();

  const int lg = l >> 4;
  const int ln = l & 15;

  float xr[4][4];
  #pragma unroll
  for (int rt = 0; rt < 4; ++rt)
    #pragma unroll
    for (int r = 0; r < 4; ++r) xr[rt][r] = x2s[rt * 16 + lg * 4 + r];
  float cv[8];
  #pragma unroll
  for (int ct = 0; ct < 8; ++ct) cv[ct] = c2s[w * 128 + ct * 16 + ln];

  float rp[4][4];
  #pragma unroll
  for (int rt = 0; rt < 4; ++rt)
    #pragma unroll
    for (int r = 0; r < 4; ++r) rp[rt][r] = 0.f;

  #pragma unroll
  for (int rt = 0; rt < 4; ++rt)
    #pragma unroll
    for (int ct = 0; ct < 8; ++ct) {
      f32x4 s = acc[rt][ct], q;
      #pragma unroll
      for (int r = 0; r < 4; ++r) {
        float d2 = xr[rt][r] + cv[ct] - 2.f * s[r];
        d2 = fmaxf(d2, 0.f);
        float qq = __builtin_amdgcn_rcpf(1.f + d2);
        q[r] = qq;
        rp[rt][r] += qq;
      }
      acc[rt][ct] = q;
    }

  #pragma unroll
  for (int m = 1; m < 16; m <<= 1)
    #pragma unroll
    for (int rt = 0; rt < 4; ++rt)
      #pragma unroll
      for (int r = 0; r < 4; ++r) rp[rt][r] += __shfl_xor(rp[rt][r], m);

  if (ln == 0)
    #pragma unroll
    for (int rt = 0; rt < 4; ++rt)
      #pragma unroll
      for (int r = 0; r < 4; ++r)
        rowsum[w][rt * 16 + lg * 4 + r] = rp[rt][r];
  __syncthreads();

  if (t < M_TILE) {
    float tot = rowsum[0][t] + rowsum[1][t] + rowsum[2][t] + rowsum[3][t];
    rinv[t] = __builtin_amdgcn_rcpf(tot);
  }
  __syncthreads();

  float ri[4][4];
  #pragma unroll
  for (int rt = 0; rt < 4; ++rt)
    #pragma unroll
    for (int r = 0; r < 4; ++r) ri[rt][r] = rinv[rt * 16 + lg * 4 + r];

  // nontemporal stores: keep the 268 MB write stream from evicting L2-resident pb
  #pragma unroll
  for (int rt = 0; rt < 4; ++rt)
    #pragma unroll
    for (int ct = 0; ct < 8; ++ct)
      #pragma unroll
      for (int r = 0; r < 4; ++r)
        __builtin_nontemporal_store(
            acc[rt][ct][r] * ri[rt][r],
            &out[(size_t)(row0 + rt * 16 + lg * 4 + r) * K_CL + w * 128 + ct * 16 + ln]);
}

extern "C" void kernel_launch(void* const* d_in, const int* in_sizes, int n_in,
                              void* d_out, int out_size, void* d_ws, size_t ws_size,
                              hipStream_t stream) {
  const float* x        = (const float*)d_in[0];
  const float* clusters = (const float*)d_in[1];
  float* out = (float*)d_out;

  // workspace: [pb: 512*512*2B packed bf16][c2: 512*4B]
  unsigned short* pbuf = (unsigned short*)d_ws;
  float* c2 = (float*)((char*)d_ws + (size_t)K_CL * D_DIM * sizeof(unsigned short));

  prep_c2<<<K_CL, 64, 0, stream>>>(clusters, c2);
  pack_b<<<STEPS * 32, 64, 0, stream>>>(clusters, pbuf);
  cluster_main<<<N_ROWS / M_TILE, 256, 0, stream>>>(x, pbuf, c2, out);
}